// Round 7
// baseline (1612.436 us; speedup 1.0000x reference)
//
#include <hip/hip_runtime.h>
#include <cstdint>

typedef unsigned short u16;
typedef __attribute__((ext_vector_type(8))) short short8;
typedef __attribute__((ext_vector_type(4))) float floatx4;
typedef __attribute__((ext_vector_type(4))) float f4;

#define NQP   64
#define MQP   128
#define NP    2080
#define NHH   8192
#define NOUT  10464   /* 2080 + 64 + 8192 + 128 */
#define NOUTP 10496   /* padded to 82*128 */
#define HOFF  2144    /* NP + NQP */

__device__ __forceinline__ float b2f(u16 u) {
  union { unsigned int i; float f; } v; v.i = ((unsigned int)u) << 16; return v.f;
}
__device__ __forceinline__ u16 f2b(float f) {
  union { float f; unsigned int i; } v; v.f = f;
  unsigned int r = v.i + 0x7fffu + ((v.i >> 16) & 1u);
  return (u16)(r >> 16);
}

// ---------------------------------------------------------------------------
// dtype detector (flag=1 -> inputs are f32)
// ---------------------------------------------------------------------------
__global__ __launch_bounds__(256) void detect_dtype(const u16* __restrict__ w,
                                                    int* __restrict__ flag) {
  __shared__ int cnt;
  if (threadIdx.x == 0) cnt = 0;
  __syncthreads();
  int c = 0;
  for (int i = threadIdx.x; i < 16384; i += 256) {
    const int e = (w[i] >> 7) & 0xFF;
    if (e >= 130 || e <= 90) ++c;
  }
  atomicAdd(&cnt, c);
  __syncthreads();
  if (threadIdx.x == 0) flag[0] = (cnt > 3000) ? 1 : 0;
}

__device__ __forceinline__ u16 load_elem_bf16(const void* p, size_t idx, int isf32) {
  return isf32 ? f2b(((const float*)p)[idx]) : ((const u16*)p)[idx];
}

__global__ __launch_bounds__(256) void convert_bf16(const void* __restrict__ in,
                                                    u16* __restrict__ out, int n,
                                                    const int* __restrict__ flag) {
  const int isf = flag[0];
  for (int i = blockIdx.x * 256 + threadIdx.x; i < n; i += gridDim.x * 256)
    out[i] = load_elem_bf16(in, i, isf);
}

// all three biases in one launch
__global__ __launch_bounds__(256) void conv_biases(const void* __restrict__ b1,
                                                   const void* __restrict__ b2,
                                                   const void* __restrict__ b3,
                                                   float* __restrict__ bf1,
                                                   float* __restrict__ bf2,
                                                   float* __restrict__ bf3,
                                                   const int* __restrict__ flag) {
  const int isf = flag[0];
  const int i = blockIdx.x * 256 + threadIdx.x;
  if (i < 1024) {
    bf1[i] = isf ? ((const float*)b1)[i] : b2f(((const u16*)b1)[i]);
  } else if (i < 2048) {
    const int j = i - 1024;
    bf2[j] = isf ? ((const float*)b2)[j] : b2f(((const u16*)b2)[j]);
  } else if (i < 2048 + NOUT) {
    const int j = i - 2048;
    bf3[j] = isf ? ((const float*)b3)[j] : b2f(((const u16*)b3)[j]);
  }
}

// ---------------------------------------------------------------------------
// All three weight transposes in one launch.
// ---------------------------------------------------------------------------
__global__ __launch_bounds__(256) void transpose_all(const void* __restrict__ W1,
                                                     const void* __restrict__ W2,
                                                     const void* __restrict__ W3,
                                                     u16* __restrict__ W1t,
                                                     u16* __restrict__ W2t,
                                                     u16* __restrict__ W3t,
                                                     const int* __restrict__ flag) {
  const int bx = blockIdx.x, by = blockIdx.y;
  const void* in; u16* out; int K, N, Npad, bxo;
  if (bx < 32)      { in = W1; out = W1t; K = 512;  N = 1024; Npad = 1024;  bxo = 0;
                      if (by >= 16) return; }
  else if (bx < 64) { in = W2; out = W2t; K = 1024; N = 1024; Npad = 1024;  bxo = 32; }
  else              { in = W3; out = W3t; K = 1024; N = NOUT; Npad = NOUTP; bxo = 64; }
  __shared__ u16 tile[32][33];
  const int isf = flag[0];
  const int n0 = (bx - bxo) * 32, k0 = by * 32;
  const int tx = threadIdx.x & 31, ty = threadIdx.x >> 5;
#pragma unroll
  for (int i = 0; i < 4; ++i) {
    const int k = k0 + ty + 8 * i, n = n0 + tx;
    tile[ty + 8 * i][tx] = (n < N) ? load_elem_bf16(in, (size_t)k * N + n, isf) : (u16)0;
  }
  __syncthreads();
#pragma unroll
  for (int i = 0; i < 4; ++i) {
    const int n = n0 + ty + 8 * i, k = k0 + tx;
    if (n < Npad) out[(size_t)n * K + k] = tile[tx][ty + 8 * i];
  }
}

// ---------------------------------------------------------------------------
// GEMM (m97-style 128x128 tile), unchanged.
// ---------------------------------------------------------------------------
__device__ __forceinline__ void gload_lds16(const u16* g, u16* l) {
  __builtin_amdgcn_global_load_lds((const __attribute__((address_space(1))) void*)g,
                                   (__attribute__((address_space(3))) void*)l, 16, 0, 0);
}

template <int EPI, bool HAS_LO>
__global__ __launch_bounds__(256) void gemm_bt(const u16* __restrict__ Ahi, const u16* __restrict__ Alo,
                                               const u16* __restrict__ Bt,  const float* __restrict__ bias,
                                               u16* __restrict__ Chi, u16* __restrict__ Clo,
                                               float* __restrict__ Cf,
                                               int M, int N, int K) {
  __shared__ __align__(16) u16 lA[128 * 32];
  __shared__ __align__(16) u16 lAlo[128 * 32];
  __shared__ __align__(16) u16 lB[128 * 32];
  const int tile_n = blockIdx.x * 128;
  const int tile_m = blockIdx.y * 128;
  const int lane = threadIdx.x & 63;
  const int wv   = threadIdx.x >> 6;
  const int wm = (wv & 1) * 64;
  const int wn = (wv >> 1) * 64;
  const int sr = lane >> 2;
  const int sk = (lane & 3) * 8;
  floatx4 acc[4][4] = {};

  for (int k0 = 0; k0 < K; k0 += 32) {
#pragma unroll
    for (int it = 0; it < 2; ++it) {
      const int slot = it * 4 + wv;
      const int r = slot * 16 + sr;
      gload_lds16(Ahi + (size_t)(tile_m + r) * K + k0 + sk, lA + slot * 512);
      if (HAS_LO)
        gload_lds16(Alo + (size_t)(tile_m + r) * K + k0 + sk, lAlo + slot * 512);
      gload_lds16(Bt + (size_t)(tile_n + r) * K + k0 + sk, lB + slot * 512);
    }
    __syncthreads();
    const int ro = lane & 15;
    const int qo = (lane >> 4) * 8;
    short8 af[4], bfr[4], al[4];
#pragma unroll
    for (int i = 0; i < 4; ++i) af[i] = *(const short8*)(lA + (wm + i * 16 + ro) * 32 + qo);
#pragma unroll
    for (int j = 0; j < 4; ++j) bfr[j] = *(const short8*)(lB + (wn + j * 16 + ro) * 32 + qo);
    if (HAS_LO) {
#pragma unroll
      for (int i = 0; i < 4; ++i) al[i] = *(const short8*)(lAlo + (wm + i * 16 + ro) * 32 + qo);
    }
#pragma unroll
    for (int i = 0; i < 4; ++i)
#pragma unroll
      for (int j = 0; j < 4; ++j) {
        acc[i][j] = __builtin_amdgcn_mfma_f32_16x16x32_bf16(af[i], bfr[j], acc[i][j], 0, 0, 0);
        if (HAS_LO)
          acc[i][j] = __builtin_amdgcn_mfma_f32_16x16x32_bf16(al[i], bfr[j], acc[i][j], 0, 0, 0);
      }
    __syncthreads();
  }

  const int colb = tile_n + wn + (lane & 15);
  const int rowb = tile_m + wm + (lane >> 4) * 4;
#pragma unroll
  for (int j = 0; j < 4; ++j) {
    const int col = colb + j * 16;
    const float bv = (col < N) ? bias[col] : 0.f;
#pragma unroll
    for (int i = 0; i < 4; ++i) {
#pragma unroll
      for (int v = 0; v < 4; ++v) {
        const int row = rowb + i * 16 + v;
        float val = acc[i][j][v] + bv;
        if (EPI == 0) {
          val = fmaxf(val, 0.f);
          const u16 hi = f2b(val);
          const float lo = val - b2f(hi);
          Chi[(size_t)row * N + col] = hi;
          Clo[(size_t)row * N + col] = f2b(lo);
        } else {
          if (col < N) Cf[(size_t)row * N + col] = val;
        }
      }
    }
  }
}

// ---------------------------------------------------------------------------
// QP helpers
// ---------------------------------------------------------------------------
__device__ __forceinline__ f4 ld4s(const float* p) { return *(const f4*)p; }
__device__ __forceinline__ void st4s(float* p, f4 v) { *(f4*)p = v; }
__device__ __forceinline__ float dot4(f4 a, f4 b) {
  return fmaf(a.x, b.x, fmaf(a.y, b.y, fmaf(a.z, b.z, a.w * b.w)));
}

// ---------------------------------------------------------------------------
// Per-batch QP solver, register-resident H, 256 threads, quarter-split roles.
// Persistent per-lane state: R (H row t&127, 16 f4) + HTq (H^T quarter, 8 f4)
// + Mq (Minv quarter-row, 4 f4) = 112 VGPR. All loop LDS reads are uniform
// broadcasts or stride-1 b32 (conflict-free). 5 barriers / PDHG iter.
// ---------------------------------------------------------------------------
__global__ __launch_bounds__(256, 3) void qp_solve(const float* __restrict__ outbuf,
                                                   void* __restrict__ xs,
                                                   const int* __restrict__ flag) {
  __shared__ __align__(16) float Ld[64 * 68];     // setup only (dense zero-padded L)
  __shared__ __align__(16) float xb_sh[64];
  __shared__ __align__(16) float lam_sh[128];     // also power-iter w
  __shared__ __align__(16) float upart[4][64];
  __shared__ __align__(16) float cpart[4][64];
  __shared__ __align__(16) float rhs_sh[64];
  __shared__ __align__(16) float q_sh[64];
  __shared__ __align__(16) float c0_sh[64];
  __shared__ __align__(16) float prow2[2][64];
  __shared__ __align__(16) float fcol2[2][64];
  __shared__ float tau_sh;

  const int t = threadIdx.x;
  const int w = t >> 6;          // wave / quarter id
  const int l = t & 63;
  const int ma = t & 127;        // A-role row (duplicated x2)
  const int isf = flag[0];
  const float* ob = outbuf + (size_t)blockIdx.x * NOUT;

  // ---- stage dense zero-padded L ----
  for (int e = t; e < 64 * 68; e += 256) Ld[e] = 0.f;
  if (t < 64) q_sh[t] = ob[NP + t];
  __syncthreads();
  for (int e = t; e < NP; e += 256) {
    int i = (int)((sqrtf(8.f * (float)e + 1.f) - 1.f) * 0.5f);
    while ((i + 1) * (i + 2) / 2 <= e) ++i;
    while (i * (i + 1) / 2 > e) --i;
    const int j = e - i * (i + 1) / 2;   // j <= i
    Ld[i * 68 + j] = ob[e];
  }
  __syncthreads();
  if (t < 64) {
    const float xv = Ld[t * 68 + t];
    Ld[t * 68 + t] = 0.1f + (fmaxf(xv, 0.f) + log1pf(expf(-fabsf(xv))));
  }
  __syncthreads();

  // ---- P quarter-row into Mq: row l, cols [16w,16w+16). Zero-padding of L
  //      rows makes a constant 17-f4 dot correct for any min(i,j). ----
  f4 Mq[4];
  {
    f4 Lrow[17];
#pragma unroll
    for (int g = 0; g < 17; ++g) Lrow[g] = ld4s(&Ld[l * 68 + 4 * g]);
#pragma unroll
    for (int u = 0; u < 4; ++u) {
      f4 acc;
#pragma unroll
      for (int c = 0; c < 4; ++c) {
        const int j = 16 * w + 4 * u + c;     // uniform within wave
        float s = 0.f, s2 = 0.f;
#pragma unroll
        for (int g = 0; g < 16; g += 2) {
          s  += dot4(Lrow[g],     ld4s(&Ld[j * 68 + 4 * g]));
          s2 += dot4(Lrow[g + 1], ld4s(&Ld[j * 68 + 4 * g + 4]));
        }
        s += dot4(Lrow[16], ld4s(&Ld[j * 68 + 64]));
        acc[c] = s + s2;
      }
      Mq[u] = acc;
    }
  }

  // ---- H into registers ----
  f4 R[16];     // full row ma
#pragma unroll
  for (int g = 0; g < 16; ++g) R[g] = *(const f4*)(ob + HOFF + (size_t)ma * 64 + 4 * g);
  f4 HTq[8];    // H[32w+j][l], j = 0..31
#pragma unroll
  for (int j = 0; j < 32; ++j) HTq[j >> 2][j & 3] = ob[HOFF + (size_t)(32 * w + j) * 64 + l];
  const float bm = ob[HOFF + NHH + ma];

  // ---- power iteration (10) ----
  if (t < 64) xb_sh[t] = 0.125f;
  __syncthreads();
  for (int pi = 0; pi < 10; ++pi) {
    float s = 0.f, s2 = 0.f;
#pragma unroll
    for (int g = 0; g < 16; g += 2) {
      s  += dot4(R[g],     ld4s(&xb_sh[4 * g]));
      s2 += dot4(R[g + 1], ld4s(&xb_sh[4 * g + 4]));
    }
    if (t < 128) lam_sh[ma] = s + s2;
    __syncthreads();
    float u = 0.f;
#pragma unroll
    for (int jg = 0; jg < 8; ++jg) u += dot4(HTq[jg], ld4s(&lam_sh[32 * w + 4 * jg]));
    upart[w][l] = u;
    __syncthreads();
    if (t < 64) {
      const float uu = upart[0][t] + upart[1][t] + upart[2][t] + upart[3][t];
      float ss = uu * uu;
#pragma unroll
      for (int o = 1; o <= 32; o <<= 1) ss += __shfl_xor(ss, o, 64);
      xb_sh[t] = uu / (sqrtf(ss) + 1e-12f);
    }
    __syncthreads();
  }
  // ---- tau ----
  {
    float s = 0.f, s2 = 0.f;
#pragma unroll
    for (int g = 0; g < 16; g += 2) {
      s  += dot4(R[g],     ld4s(&xb_sh[4 * g]));
      s2 += dot4(R[g + 1], ld4s(&xb_sh[4 * g + 4]));
    }
    if (t < 128) lam_sh[ma] = s + s2;
    __syncthreads();
    if (t < 64) {
      const float a = lam_sh[t], bb = lam_sh[t + 64];
      float ss = a * a + bb * bb;
#pragma unroll
      for (int o = 1; o <= 32; o <<= 1) ss += __shfl_xor(ss, o, 64);
      if (t == 0) tau_sh = 0.9f / (sqrtf(ss) + 1e-6f);
    }
    __syncthreads();
  }
  const float tau = tau_sh;

  // ---- M = I + tau*P ----
#pragma unroll
  for (int u = 0; u < 4; ++u) {
    f4 m = Mq[u] * tau;
    m.x += (16 * w + 4 * u + 0 == l) ? 1.f : 0.f;
    m.y += (16 * w + 4 * u + 1 == l) ? 1.f : 0.f;
    m.z += (16 * w + 4 * u + 2 == l) ? 1.f : 0.f;
    m.w += (16 * w + 4 * u + 3 == l) ? 1.f : 0.f;
    Mq[u] = m;
  }

  // ---- Gauss-Jordan on quarter-rows (SPD, pivots >= 1), 1 barrier/k ----
  if (l == 0) {
#pragma unroll
    for (int u = 0; u < 4; ++u) st4s(&prow2[0][16 * w + 4 * u], Mq[u]);
  }
  if (w == 0) fcol2[0][l] = Mq[0].x;
  __syncthreads();
#pragma unroll
  for (int k = 0; k < 64; ++k) {
    const int kb = k & 1;
    const float d = 1.0f / prow2[kb][k];
    const float f = fcol2[kb][l];
    const bool piv = (l == k);
#pragma unroll
    for (int u = 0; u < 4; ++u) {
      const f4 pr = ld4s(&prow2[kb][16 * w + 4 * u]);
      const f4 prd = pr * d;
      f4 m = Mq[u];
      m.x = piv ? prd.x : fmaf(-f, prd.x, m.x);
      m.y = piv ? prd.y : fmaf(-f, prd.y, m.y);
      m.z = piv ? prd.z : fmaf(-f, prd.z, m.z);
      m.w = piv ? prd.w : fmaf(-f, prd.w, m.w);
      Mq[u] = m;
    }
    if ((k >> 4) == w) {
      const float v = piv ? d : -f * d;
      f4 m = Mq[(k & 15) >> 2];
      if ((k & 3) == 0) m.x = v; else if ((k & 3) == 1) m.y = v;
      else if ((k & 3) == 2) m.z = v; else m.w = v;
      Mq[(k & 15) >> 2] = m;
    }
    if (k < 63) {
      if (l == k + 1) {
#pragma unroll
        for (int u = 0; u < 4; ++u) st4s(&prow2[1 - kb][16 * w + 4 * u], Mq[u]);
      }
      const int kn = k + 1;
      if ((kn >> 4) == w) {
        const f4 m = Mq[(kn & 15) >> 2];
        const float e = (kn & 3) == 0 ? m.x : (kn & 3) == 1 ? m.y
                       : (kn & 3) == 2 ? m.z : m.w;
        fcol2[1 - kb][l] = e;
      }
    }
    __syncthreads();
  }

  // ---- c0 = tau * Minv q ----
  {
    float cd = 0.f;
#pragma unroll
    for (int u = 0; u < 4; ++u) cd += dot4(Mq[u], ld4s(&q_sh[16 * w + 4 * u]));
    cpart[w][l] = cd;
    __syncthreads();
    if (t < 64) c0_sh[t] = tau * (cpart[0][t] + cpart[1][t] + cpart[2][t] + cpart[3][t]);
  }
  float lam = 0.f, xp = 0.f;
  if (t < 64) xb_sh[t] = 0.f;
  __syncthreads();

  // ---- PDHG (50 iters), 5 barriers/iter ----
  for (int it = 0; it < 50; ++it) {
    float s = 0.f, s2 = 0.f;
#pragma unroll
    for (int g = 0; g < 16; g += 2) {
      s  += dot4(R[g],     ld4s(&xb_sh[4 * g]));
      s2 += dot4(R[g + 1], ld4s(&xb_sh[4 * g + 4]));
    }
    lam = fmaxf(lam - tau * ((s + s2) + bm), 0.f);
    if (t < 128) lam_sh[ma] = lam;
    __syncthreads();
    float u = 0.f;
#pragma unroll
    for (int jg = 0; jg < 8; ++jg) u += dot4(HTq[jg], ld4s(&lam_sh[32 * w + 4 * jg]));
    upart[w][l] = u;
    __syncthreads();
    if (t < 64) rhs_sh[t] = xp + tau * (upart[0][t] + upart[1][t] + upart[2][t] + upart[3][t]);
    __syncthreads();
    float cd = 0.f;
#pragma unroll
    for (int u4 = 0; u4 < 4; ++u4) cd += dot4(Mq[u4], ld4s(&rhs_sh[16 * w + 4 * u4]));
    cpart[w][l] = cd;
    __syncthreads();
    if (t < 64) {
      const float xn = (cpart[0][t] + cpart[1][t] + cpart[2][t] + cpart[3][t]) - c0_sh[t];
      xb_sh[t] = 2.f * xn - xp;
      xp = xn;
    }
    __syncthreads();
  }

  if (t < 64) {
    const size_t oi = (size_t)blockIdx.x * NQP + t;
    if (isf) ((float*)xs)[oi] = xp;
    else     ((u16*)xs)[oi]   = f2b(xp);
  }
}

// ---------------------------------------------------------------------------
extern "C" void kernel_launch(void* const* d_in, const int* in_sizes, int n_in,
                              void* d_out, int out_size, void* d_ws, size_t ws_size,
                              hipStream_t stream) {
  const void* x  = d_in[0];
  const void* W1 = d_in[1];
  const void* b1 = d_in[2];
  const void* W2 = d_in[3];
  const void* b2 = d_in[4];
  const void* W3 = d_in[5];
  const void* b3 = d_in[6];

  char* ws = (char*)d_ws;
  size_t off = 0;
  auto take = [&](size_t bytes) -> char* {
    char* r = ws + off;
    off += (bytes + 255) & ~(size_t)255;
    return r;
  };
  int*   flag = (int*)take(256);
  float* bf1  = (float*)take(1024 * 4);
  float* bf2  = (float*)take(1024 * 4);
  float* bf3  = (float*)take((size_t)NOUT * 4);
  u16*   W3t  = (u16*)take((size_t)NOUTP * 1024 * 2);
  u16*   h2hi = (u16*)take(1024ull * 1024 * 2);
  u16*   h2lo = (u16*)take(1024ull * 1024 * 2);
  char*  region = take(1024ull * NOUT * 4);   // outf, overlaid below
  float* outf = (float*)region;
  u16* xb   = (u16*)(region + 0);                 // 1 MB
  u16* W1t  = (u16*)(region + (1u << 20));        // 1 MB
  u16* W2t  = (u16*)(region + (2u << 20));        // 2 MB
  u16* h1hi = (u16*)(region + (4u << 20));        // 2 MB
  u16* h1lo = (u16*)(region + (6u << 20));        // 2 MB
  (void)ws_size; (void)in_sizes; (void)n_in; (void)out_size;

  detect_dtype<<<dim3(1), 256, 0, stream>>>((const u16*)W1, flag);

  convert_bf16<<<dim3(512), 256, 0, stream>>>(x, xb, 1024 * 512, flag);
  conv_biases<<<dim3(49), 256, 0, stream>>>(b1, b2, b3, bf1, bf2, bf3, flag);
  transpose_all<<<dim3(392, 32), 256, 0, stream>>>(W1, W2, W3, W1t, W2t, W3t, flag);

  gemm_bt<0, false><<<dim3(8, 8), 256, 0, stream>>>(xb, nullptr, W1t, bf1,
                                                    h1hi, h1lo, nullptr, 1024, 1024, 512);
  gemm_bt<0, true><<<dim3(8, 8), 256, 0, stream>>>(h1hi, h1lo, W2t, bf2,
                                                   h2hi, h2lo, nullptr, 1024, 1024, 1024);
  gemm_bt<1, true><<<dim3(NOUTP / 128, 8), 256, 0, stream>>>(h2hi, h2lo, W3t, bf3,
                                                             nullptr, nullptr, outf, 1024, NOUT, 1024);
  qp_solve<<<dim3(1024), 256, 0, stream>>>(outf, d_out, flag);
}

// Round 8
// 548.586 us; speedup vs baseline: 2.9393x; 2.9393x over previous
//
#include <hip/hip_runtime.h>
#include <cstdint>

typedef unsigned short u16;
typedef __attribute__((ext_vector_type(8))) short short8;
typedef __attribute__((ext_vector_type(4))) float floatx4;
typedef __attribute__((ext_vector_type(4))) float f4;

#define NQP   64
#define MQP   128
#define NP    2080
#define NHH   8192
#define NOUT  10464   /* 2080 + 64 + 8192 + 128 */
#define NOUTP 10496   /* padded to 82*128 */
#define HOFF  2144    /* NP + NQP */

__device__ __forceinline__ float b2f(u16 u) {
  union { unsigned int i; float f; } v; v.i = ((unsigned int)u) << 16; return v.f;
}
__device__ __forceinline__ u16 f2b(float f) {
  union { float f; unsigned int i; } v; v.f = f;
  unsigned int r = v.i + 0x7fffu + ((v.i >> 16) & 1u);
  return (u16)(r >> 16);
}

// wave-local LDS fence: all of this wave's LDS writes complete & compiler
// may not reorder across it. No cross-wave wait.
__device__ __forceinline__ void wfence() {
  __builtin_amdgcn_wave_barrier();
  __threadfence_block();
  __builtin_amdgcn_wave_barrier();
}

// ---------------------------------------------------------------------------
// dtype detector (flag=1 -> inputs are f32)
// ---------------------------------------------------------------------------
__global__ __launch_bounds__(256) void detect_dtype(const u16* __restrict__ w,
                                                    int* __restrict__ flag) {
  __shared__ int cnt;
  if (threadIdx.x == 0) cnt = 0;
  __syncthreads();
  int c = 0;
  for (int i = threadIdx.x; i < 16384; i += 256) {
    const int e = (w[i] >> 7) & 0xFF;
    if (e >= 130 || e <= 90) ++c;
  }
  atomicAdd(&cnt, c);
  __syncthreads();
  if (threadIdx.x == 0) flag[0] = (cnt > 3000) ? 1 : 0;
}

__device__ __forceinline__ u16 load_elem_bf16(const void* p, size_t idx, int isf32) {
  return isf32 ? f2b(((const float*)p)[idx]) : ((const u16*)p)[idx];
}

__global__ __launch_bounds__(256) void convert_bf16(const void* __restrict__ in,
                                                    u16* __restrict__ out, int n,
                                                    const int* __restrict__ flag) {
  const int isf = flag[0];
  for (int i = blockIdx.x * 256 + threadIdx.x; i < n; i += gridDim.x * 256)
    out[i] = load_elem_bf16(in, i, isf);
}

// all three biases in one launch
__global__ __launch_bounds__(256) void conv_biases(const void* __restrict__ b1,
                                                   const void* __restrict__ b2,
                                                   const void* __restrict__ b3,
                                                   float* __restrict__ bf1,
                                                   float* __restrict__ bf2,
                                                   float* __restrict__ bf3,
                                                   const int* __restrict__ flag) {
  const int isf = flag[0];
  const int i = blockIdx.x * 256 + threadIdx.x;
  if (i < 1024) {
    bf1[i] = isf ? ((const float*)b1)[i] : b2f(((const u16*)b1)[i]);
  } else if (i < 2048) {
    const int j = i - 1024;
    bf2[j] = isf ? ((const float*)b2)[j] : b2f(((const u16*)b2)[j]);
  } else if (i < 2048 + NOUT) {
    const int j = i - 2048;
    bf3[j] = isf ? ((const float*)b3)[j] : b2f(((const u16*)b3)[j]);
  }
}

// ---------------------------------------------------------------------------
// All three weight transposes in one launch.
// ---------------------------------------------------------------------------
__global__ __launch_bounds__(256) void transpose_all(const void* __restrict__ W1,
                                                     const void* __restrict__ W2,
                                                     const void* __restrict__ W3,
                                                     u16* __restrict__ W1t,
                                                     u16* __restrict__ W2t,
                                                     u16* __restrict__ W3t,
                                                     const int* __restrict__ flag) {
  const int bx = blockIdx.x, by = blockIdx.y;
  const void* in; u16* out; int K, N, Npad, bxo;
  if (bx < 32)      { in = W1; out = W1t; K = 512;  N = 1024; Npad = 1024;  bxo = 0;
                      if (by >= 16) return; }
  else if (bx < 64) { in = W2; out = W2t; K = 1024; N = 1024; Npad = 1024;  bxo = 32; }
  else              { in = W3; out = W3t; K = 1024; N = NOUT; Npad = NOUTP; bxo = 64; }
  __shared__ u16 tile[32][33];
  const int isf = flag[0];
  const int n0 = (bx - bxo) * 32, k0 = by * 32;
  const int tx = threadIdx.x & 31, ty = threadIdx.x >> 5;
#pragma unroll
  for (int i = 0; i < 4; ++i) {
    const int k = k0 + ty + 8 * i, n = n0 + tx;
    tile[ty + 8 * i][tx] = (n < N) ? load_elem_bf16(in, (size_t)k * N + n, isf) : (u16)0;
  }
  __syncthreads();
#pragma unroll
  for (int i = 0; i < 4; ++i) {
    const int n = n0 + ty + 8 * i, k = k0 + tx;
    if (n < Npad) out[(size_t)n * K + k] = tile[tx][ty + 8 * i];
  }
}

// ---------------------------------------------------------------------------
// GEMM (m97-style 128x128 tile), unchanged.
// ---------------------------------------------------------------------------
__device__ __forceinline__ void gload_lds16(const u16* g, u16* l) {
  __builtin_amdgcn_global_load_lds((const __attribute__((address_space(1))) void*)g,
                                   (__attribute__((address_space(3))) void*)l, 16, 0, 0);
}

template <int EPI, bool HAS_LO>
__global__ __launch_bounds__(256) void gemm_bt(const u16* __restrict__ Ahi, const u16* __restrict__ Alo,
                                               const u16* __restrict__ Bt,  const float* __restrict__ bias,
                                               u16* __restrict__ Chi, u16* __restrict__ Clo,
                                               float* __restrict__ Cf,
                                               int M, int N, int K) {
  __shared__ __align__(16) u16 lA[128 * 32];
  __shared__ __align__(16) u16 lAlo[128 * 32];
  __shared__ __align__(16) u16 lB[128 * 32];
  const int tile_n = blockIdx.x * 128;
  const int tile_m = blockIdx.y * 128;
  const int lane = threadIdx.x & 63;
  const int wv   = threadIdx.x >> 6;
  const int wm = (wv & 1) * 64;
  const int wn = (wv >> 1) * 64;
  const int sr = lane >> 2;
  const int sk = (lane & 3) * 8;
  floatx4 acc[4][4] = {};

  for (int k0 = 0; k0 < K; k0 += 32) {
#pragma unroll
    for (int it = 0; it < 2; ++it) {
      const int slot = it * 4 + wv;
      const int r = slot * 16 + sr;
      gload_lds16(Ahi + (size_t)(tile_m + r) * K + k0 + sk, lA + slot * 512);
      if (HAS_LO)
        gload_lds16(Alo + (size_t)(tile_m + r) * K + k0 + sk, lAlo + slot * 512);
      gload_lds16(Bt + (size_t)(tile_n + r) * K + k0 + sk, lB + slot * 512);
    }
    __syncthreads();
    const int ro = lane & 15;
    const int qo = (lane >> 4) * 8;
    short8 af[4], bfr[4], al[4];
#pragma unroll
    for (int i = 0; i < 4; ++i) af[i] = *(const short8*)(lA + (wm + i * 16 + ro) * 32 + qo);
#pragma unroll
    for (int j = 0; j < 4; ++j) bfr[j] = *(const short8*)(lB + (wn + j * 16 + ro) * 32 + qo);
    if (HAS_LO) {
#pragma unroll
      for (int i = 0; i < 4; ++i) al[i] = *(const short8*)(lAlo + (wm + i * 16 + ro) * 32 + qo);
    }
#pragma unroll
    for (int i = 0; i < 4; ++i)
#pragma unroll
      for (int j = 0; j < 4; ++j) {
        acc[i][j] = __builtin_amdgcn_mfma_f32_16x16x32_bf16(af[i], bfr[j], acc[i][j], 0, 0, 0);
        if (HAS_LO)
          acc[i][j] = __builtin_amdgcn_mfma_f32_16x16x32_bf16(al[i], bfr[j], acc[i][j], 0, 0, 0);
      }
    __syncthreads();
  }

  const int colb = tile_n + wn + (lane & 15);
  const int rowb = tile_m + wm + (lane >> 4) * 4;
#pragma unroll
  for (int j = 0; j < 4; ++j) {
    const int col = colb + j * 16;
    const float bv = (col < N) ? bias[col] : 0.f;
#pragma unroll
    for (int i = 0; i < 4; ++i) {
#pragma unroll
      for (int v = 0; v < 4; ++v) {
        const int row = rowb + i * 16 + v;
        float val = acc[i][j][v] + bv;
        if (EPI == 0) {
          val = fmaxf(val, 0.f);
          const u16 hi = f2b(val);
          const float lo = val - b2f(hi);
          Chi[(size_t)row * N + col] = hi;
          Clo[(size_t)row * N + col] = f2b(lo);
        } else {
          if (col < N) Cf[(size_t)row * N + col] = val;
        }
      }
    }
  }
}

// ---------------------------------------------------------------------------
// QP helpers
// ---------------------------------------------------------------------------
__device__ __forceinline__ f4 ld4s(const float* p) { return *(const f4*)p; }
__device__ __forceinline__ void st4s(float* p, f4 v) { *(f4*)p = v; }
__device__ __forceinline__ float dot4(f4 a, f4 b) {
  return fmaf(a.x, b.x, fmaf(a.y, b.y, fmaf(a.z, b.z, a.w * b.w)));
}
__device__ __forceinline__ f4 shx4(f4 v, int m) {
  f4 r;
  r.x = __shfl_xor(v.x, m, 64); r.y = __shfl_xor(v.y, m, 64);
  r.z = __shfl_xor(v.z, m, 64); r.w = __shfl_xor(v.w, m, 64);
  return r;
}
// XOR-swizzled float-index of f4 group g in row m (row stride 64 floats).
__device__ __forceinline__ int hQ(int m, int g) {
  return (m << 6) + (((g ^ (m & 15))) << 2);
}

// ---------------------------------------------------------------------------
// Per-batch QP solver: R5 structure (proven spill-free) with barrier surgery.
// PDHG iter: 2 barriers (was 4). A->B via in-wave shfl of lam; rhs computed
// redundantly by all waves; xbar passed through per-wave buffer + wave fence.
// ---------------------------------------------------------------------------
__global__ __launch_bounds__(256, 4) void qp_solve(const float* __restrict__ outbuf,
                                                   void* __restrict__ xs,
                                                   const int* __restrict__ flag) {
  __shared__ __align__(16) float H_s[8192];       // 32 KB (setup: Ld stride-68 + packed p)
  __shared__ __align__(16) float xb_sh[64];       // power-iter vector
  __shared__ __align__(16) float lam_sh[128];     // power-iter w staging
  __shared__ __align__(16) float upart[4][64];
  __shared__ __align__(16) float cpart[4][64];
  __shared__ __align__(16) float q_sh[64];
  __shared__ __align__(16) float wbuf[4][64];     // per-wave xbar copies
  __shared__ __align__(16) float prow2[2][64];
  __shared__ __align__(16) float fcol2[2][64];
  __shared__ float tau_sh;

  const int t = threadIdx.x;
  const int w = t >> 6;          // wave / quarter id
  const int l = t & 63;
  const int am = 32 * w + (l >> 1), as = l & 1;    // phase-A: row m, half s
  const int bg = l & 15, bc = l >> 4;              // phase-B: n-group, m-chunk
  const int isf = flag[0];
  const float* ob = outbuf + (size_t)blockIdx.x * NOUT;

  // ---- stage dense zero-padded L ----
  float* Ld = H_s;                 // [0 .. 64*68)
  for (int e = t; e < 64 * 68; e += 256) Ld[e] = 0.f;
  if (t < 64) q_sh[t] = ob[NP + t];
  __syncthreads();
  for (int e = t; e < NP; e += 256) {
    int i = (int)((sqrtf(8.f * (float)e + 1.f) - 1.f) * 0.5f);
    while ((i + 1) * (i + 2) / 2 <= e) ++i;
    while (i * (i + 1) / 2 > e) --i;
    const int j = e - i * (i + 1) / 2;   // j <= i
    Ld[i * 68 + j] = ob[e];
  }
  __syncthreads();
  if (t < 64) {
    const float xv = Ld[t * 68 + t];
    Ld[t * 68 + t] = 0.1f + (fmaxf(xv, 0.f) + log1pf(expf(-fabsf(xv))));
  }
  __syncthreads();

  // ---- P quarter-row into Mq: row l, cols [16w,16w+16) ----
  f4 Mq[4];
  {
    f4 Lrow[17];
#pragma unroll
    for (int g = 0; g < 17; ++g) Lrow[g] = ld4s(&Ld[l * 68 + 4 * g]);
#pragma unroll
    for (int u = 0; u < 4; ++u) {
      f4 acc;
#pragma unroll
      for (int c = 0; c < 4; ++c) {
        const int j = 16 * w + 4 * u + c;     // uniform within wave
        float s = 0.f, s2 = 0.f;
#pragma unroll
        for (int g = 0; g < 16; g += 2) {
          s  += dot4(Lrow[g],     ld4s(&Ld[j * 68 + 4 * g]));
          s2 += dot4(Lrow[g + 1], ld4s(&Ld[j * 68 + 4 * g + 4]));
        }
        s += dot4(Lrow[16], ld4s(&Ld[j * 68 + 64]));
        acc[c] = s + s2;
      }
      Mq[u] = acc;
    }
  }
  __syncthreads();   // done with Ld

  // ---- load H (swizzled f32) ----
  for (int e = t; e < NHH; e += 256) {
    const int m = e >> 6, n = e & 63;
    H_s[hQ(m, n >> 2) + (n & 3)] = ob[NP + NQP + e];
  }
  const float bm = ob[HOFF + NHH + am];
  if (t < 64) xb_sh[t] = 0.125f;
  __syncthreads();

  // ---- power iteration (10) — unchanged R5 structure ----
  for (int pi = 0; pi < 10; ++pi) {
    {
      float s = 0.f;
#pragma unroll
      for (int k = 0; k < 8; ++k) {
        const int g = 8 * as + k;
        s += dot4(ld4s(&H_s[hQ(am, g)]), ld4s(&xb_sh[4 * g]));
      }
      s += __shfl_xor(s, 1, 64);
      if (as == 0) lam_sh[am] = s;
    }
    __syncthreads();
    {
      f4 u = {0.f, 0.f, 0.f, 0.f};
#pragma unroll
      for (int k = 0; k < 8; ++k) {
        const int m = 32 * w + 8 * bc + k;
        u += ld4s(&H_s[hQ(m, bg)]) * lam_sh[m];
      }
      u += shx4(u, 16); u += shx4(u, 32);
      if (l < 16) st4s(&upart[w][4 * bg], u);
    }
    __syncthreads();
    if (t < 64) {
      const float uu = upart[0][t] + upart[1][t] + upart[2][t] + upart[3][t];
      float ss = uu * uu;
#pragma unroll
      for (int o = 1; o <= 32; o <<= 1) ss += __shfl_xor(ss, o, 64);
      xb_sh[t] = uu / (sqrtf(ss) + 1e-12f);
    }
    __syncthreads();
  }
  // ---- tau ----
  {
    float s = 0.f;
#pragma unroll
    for (int k = 0; k < 8; ++k) {
      const int g = 8 * as + k;
      s += dot4(ld4s(&H_s[hQ(am, g)]), ld4s(&xb_sh[4 * g]));
    }
    s += __shfl_xor(s, 1, 64);
    if (as == 0) lam_sh[am] = s;
    __syncthreads();
    if (t < 64) {
      const float a = lam_sh[t], bb = lam_sh[t + 64];
      float ss = a * a + bb * bb;
#pragma unroll
      for (int o = 1; o <= 32; o <<= 1) ss += __shfl_xor(ss, o, 64);
      if (t == 0) tau_sh = 0.9f / (sqrtf(ss) + 1e-6f);
    }
    __syncthreads();
  }
  const float tau = tau_sh;

  // ---- M = I + tau*P ----
#pragma unroll
  for (int u = 0; u < 4; ++u) {
    f4 m = Mq[u] * tau;
    m.x += (16 * w + 4 * u + 0 == l) ? 1.f : 0.f;
    m.y += (16 * w + 4 * u + 1 == l) ? 1.f : 0.f;
    m.z += (16 * w + 4 * u + 2 == l) ? 1.f : 0.f;
    m.w += (16 * w + 4 * u + 3 == l) ? 1.f : 0.f;
    Mq[u] = m;
  }

  // ---- Gauss-Jordan on quarter-rows (SPD, pivots >= 1), 1 barrier/k ----
  if (l == 0) {
#pragma unroll
    for (int u = 0; u < 4; ++u) st4s(&prow2[0][16 * w + 4 * u], Mq[u]);
  }
  if (w == 0) fcol2[0][l] = Mq[0].x;
  __syncthreads();
#pragma unroll
  for (int k = 0; k < 64; ++k) {
    const int kb = k & 1;
    const float d = 1.0f / prow2[kb][k];
    const float f = fcol2[kb][l];
    const bool piv = (l == k);
#pragma unroll
    for (int u = 0; u < 4; ++u) {
      const f4 pr = ld4s(&prow2[kb][16 * w + 4 * u]);
      const f4 prd = pr * d;
      f4 m = Mq[u];
      m.x = piv ? prd.x : fmaf(-f, prd.x, m.x);
      m.y = piv ? prd.y : fmaf(-f, prd.y, m.y);
      m.z = piv ? prd.z : fmaf(-f, prd.z, m.z);
      m.w = piv ? prd.w : fmaf(-f, prd.w, m.w);
      Mq[u] = m;
    }
    if ((k >> 4) == w) {
      const float v = piv ? d : -f * d;
      f4 m = Mq[(k & 15) >> 2];
      if ((k & 3) == 0) m.x = v; else if ((k & 3) == 1) m.y = v;
      else if ((k & 3) == 2) m.z = v; else m.w = v;
      Mq[(k & 15) >> 2] = m;
    }
    if (k < 63) {
      if (l == k + 1) {
#pragma unroll
        for (int u = 0; u < 4; ++u) st4s(&prow2[1 - kb][16 * w + 4 * u], Mq[u]);
      }
      const int kn = k + 1;
      if ((kn >> 4) == w) {
        const f4 m = Mq[(kn & 15) >> 2];
        const float e = (kn & 3) == 0 ? m.x : (kn & 3) == 1 ? m.y
                       : (kn & 3) == 2 ? m.z : m.w;
        fcol2[1 - kb][l] = e;
      }
    }
    __syncthreads();
  }

  // ---- c0 = tau * Minv q (register, replicated in every lane) ----
  float c0;
  {
    float cd = 0.f;
#pragma unroll
    for (int u = 0; u < 4; ++u) cd += dot4(Mq[u], ld4s(&q_sh[16 * w + 4 * u]));
    cpart[w][l] = cd;
    __syncthreads();
    c0 = tau * (cpart[0][l] + cpart[1][l] + cpart[2][l] + cpart[3][l]);
  }

  // ---- PDHG init ----
  float lam = 0.f, xp = 0.f;
  wbuf[w][l] = 0.f;
  __syncthreads();

  // ---- PDHG (50 iters), 2 barriers/iter ----
  for (int it = 0; it < 50; ++it) {
    // A: lam = relu(lam - tau*(H xbar + b)) — reads own wave's xbar copy
    {
      float s = 0.f;
#pragma unroll
      for (int k = 0; k < 8; ++k) {
        const int g = 8 * as + k;
        s += dot4(ld4s(&H_s[hQ(am, g)]), ld4s(&wbuf[w][4 * g]));
      }
      s += __shfl_xor(s, 1, 64);
      lam = fmaxf(lam - tau * (s + bm), 0.f);
    }
    // B: per-wave partials of H^T lam — lam via in-wave shfl (no barrier)
    {
      f4 u = {0.f, 0.f, 0.f, 0.f};
#pragma unroll
      for (int k = 0; k < 8; ++k) {
        const float lm = __shfl(lam, 2 * (8 * bc + k), 64);
        const int m = 32 * w + 8 * bc + k;
        u += ld4s(&H_s[hQ(m, bg)]) * lm;
      }
      u += shx4(u, 16); u += shx4(u, 32);
      if (l < 16) st4s(&upart[w][4 * bg], u);
    }
    __syncthreads();                               // barrier #1
    // C: all lanes redundantly: rhs_l; then Mq partial via uniform shfls
    {
      const float uu = upart[0][l] + upart[1][l] + upart[2][l] + upart[3][l];
      const float rhs = xp + tau * uu;
      float cd = 0.f;
#pragma unroll
      for (int u = 0; u < 4; ++u) {
        f4 rv;
        rv.x = __shfl(rhs, 16 * w + 4 * u + 0, 64);
        rv.y = __shfl(rhs, 16 * w + 4 * u + 1, 64);
        rv.z = __shfl(rhs, 16 * w + 4 * u + 2, 64);
        rv.w = __shfl(rhs, 16 * w + 4 * u + 3, 64);
        cd += dot4(Mq[u], rv);
      }
      cpart[w][l] = cd;
    }
    __syncthreads();                               // barrier #2
    {
      const float xn = (cpart[0][l] + cpart[1][l] + cpart[2][l] + cpart[3][l]) - c0;
      wbuf[w][l] = 2.f * xn - xp;                  // own-wave xbar copy
      xp = xn;
    }
    wfence();                                      // wave-local visibility
  }

  if (t < 64) {
    const size_t oi = (size_t)blockIdx.x * NQP + t;
    if (isf) ((float*)xs)[oi] = xp;
    else     ((u16*)xs)[oi]   = f2b(xp);
  }
}

// ---------------------------------------------------------------------------
extern "C" void kernel_launch(void* const* d_in, const int* in_sizes, int n_in,
                              void* d_out, int out_size, void* d_ws, size_t ws_size,
                              hipStream_t stream) {
  const void* x  = d_in[0];
  const void* W1 = d_in[1];
  const void* b1 = d_in[2];
  const void* W2 = d_in[3];
  const void* b2 = d_in[4];
  const void* W3 = d_in[5];
  const void* b3 = d_in[6];

  char* ws = (char*)d_ws;
  size_t off = 0;
  auto take = [&](size_t bytes) -> char* {
    char* r = ws + off;
    off += (bytes + 255) & ~(size_t)255;
    return r;
  };
  int*   flag = (int*)take(256);
  float* bf1  = (float*)take(1024 * 4);
  float* bf2  = (float*)take(1024 * 4);
  float* bf3  = (float*)take((size_t)NOUT * 4);
  u16*   W3t  = (u16*)take((size_t)NOUTP * 1024 * 2);
  u16*   h2hi = (u16*)take(1024ull * 1024 * 2);
  u16*   h2lo = (u16*)take(1024ull * 1024 * 2);
  char*  region = take(1024ull * NOUT * 4);   // outf, overlaid below
  float* outf = (float*)region;
  u16* xb   = (u16*)(region + 0);                 // 1 MB
  u16* W1t  = (u16*)(region + (1u << 20));        // 1 MB
  u16* W2t  = (u16*)(region + (2u << 20));        // 2 MB
  u16* h1hi = (u16*)(region + (4u << 20));        // 2 MB
  u16* h1lo = (u16*)(region + (6u << 20));        // 2 MB
  (void)ws_size; (void)in_sizes; (void)n_in; (void)out_size;

  detect_dtype<<<dim3(1), 256, 0, stream>>>((const u16*)W1, flag);

  convert_bf16<<<dim3(512), 256, 0, stream>>>(x, xb, 1024 * 512, flag);
  conv_biases<<<dim3(49), 256, 0, stream>>>(b1, b2, b3, bf1, bf2, bf3, flag);
  transpose_all<<<dim3(392, 32), 256, 0, stream>>>(W1, W2, W3, W1t, W2t, W3t, flag);

  gemm_bt<0, false><<<dim3(8, 8), 256, 0, stream>>>(xb, nullptr, W1t, bf1,
                                                    h1hi, h1lo, nullptr, 1024, 1024, 512);
  gemm_bt<0, true><<<dim3(8, 8), 256, 0, stream>>>(h1hi, h1lo, W2t, bf2,
                                                   h2hi, h2lo, nullptr, 1024, 1024, 1024);
  gemm_bt<1, true><<<dim3(NOUTP / 128, 8), 256, 0, stream>>>(h2hi, h2lo, W3t, bf3,
                                                             nullptr, nullptr, outf, 1024, NOUT, 1024);
  qp_solve<<<dim3(1024), 256, 0, stream>>>(outf, d_out, flag);
}

// Round 9
// 491.403 us; speedup vs baseline: 3.2813x; 1.1164x over previous
//
#include <hip/hip_runtime.h>
#include <cstdint>

typedef unsigned short u16;
typedef __attribute__((ext_vector_type(8))) short short8;
typedef __attribute__((ext_vector_type(4))) float floatx4;
typedef __attribute__((ext_vector_type(4))) float f4;

#define NQP   64
#define MQP   128
#define NP    2080
#define NHH   8192
#define NOUT  10464   /* 2080 + 64 + 8192 + 128 */
#define NOUTP 10496   /* padded to 82*128 */

__device__ __forceinline__ float b2f(u16 u) {
  union { unsigned int i; float f; } v; v.i = ((unsigned int)u) << 16; return v.f;
}
__device__ __forceinline__ u16 f2b(float f) {
  union { float f; unsigned int i; } v; v.f = f;
  unsigned int r = v.i + 0x7fffu + ((v.i >> 16) & 1u);
  return (u16)(r >> 16);
}

// ---------------------------------------------------------------------------
// dtype detector (flag=1 -> inputs are f32)
// ---------------------------------------------------------------------------
__global__ __launch_bounds__(256) void detect_dtype(const u16* __restrict__ w,
                                                    int* __restrict__ flag) {
  __shared__ int cnt;
  if (threadIdx.x == 0) cnt = 0;
  __syncthreads();
  int c = 0;
  for (int i = threadIdx.x; i < 16384; i += 256) {
    const int e = (w[i] >> 7) & 0xFF;
    if (e >= 130 || e <= 90) ++c;
  }
  atomicAdd(&cnt, c);
  __syncthreads();
  if (threadIdx.x == 0) flag[0] = (cnt > 3000) ? 1 : 0;
}

__device__ __forceinline__ u16 load_elem_bf16(const void* p, size_t idx, int isf32) {
  return isf32 ? f2b(((const float*)p)[idx]) : ((const u16*)p)[idx];
}

__global__ __launch_bounds__(256) void convert_bf16(const void* __restrict__ in,
                                                    u16* __restrict__ out, int n,
                                                    const int* __restrict__ flag) {
  const int isf = flag[0];
  for (int i = blockIdx.x * 256 + threadIdx.x; i < n; i += gridDim.x * 256)
    out[i] = load_elem_bf16(in, i, isf);
}

// all three biases in one launch
__global__ __launch_bounds__(256) void conv_biases(const void* __restrict__ b1,
                                                   const void* __restrict__ b2,
                                                   const void* __restrict__ b3,
                                                   float* __restrict__ bf1,
                                                   float* __restrict__ bf2,
                                                   float* __restrict__ bf3,
                                                   const int* __restrict__ flag) {
  const int isf = flag[0];
  const int i = blockIdx.x * 256 + threadIdx.x;
  if (i < 1024) {
    bf1[i] = isf ? ((const float*)b1)[i] : b2f(((const u16*)b1)[i]);
  } else if (i < 2048) {
    const int j = i - 1024;
    bf2[j] = isf ? ((const float*)b2)[j] : b2f(((const u16*)b2)[j]);
  } else if (i < 2048 + NOUT) {
    const int j = i - 2048;
    bf3[j] = isf ? ((const float*)b3)[j] : b2f(((const u16*)b3)[j]);
  }
}

// ---------------------------------------------------------------------------
// All three weight transposes in one launch.
// ---------------------------------------------------------------------------
__global__ __launch_bounds__(256) void transpose_all(const void* __restrict__ W1,
                                                     const void* __restrict__ W2,
                                                     const void* __restrict__ W3,
                                                     u16* __restrict__ W1t,
                                                     u16* __restrict__ W2t,
                                                     u16* __restrict__ W3t,
                                                     const int* __restrict__ flag) {
  const int bx = blockIdx.x, by = blockIdx.y;
  const void* in; u16* out; int K, N, Npad, bxo;
  if (bx < 32)      { in = W1; out = W1t; K = 512;  N = 1024; Npad = 1024;  bxo = 0;
                      if (by >= 16) return; }
  else if (bx < 64) { in = W2; out = W2t; K = 1024; N = 1024; Npad = 1024;  bxo = 32; }
  else              { in = W3; out = W3t; K = 1024; N = NOUT; Npad = NOUTP; bxo = 64; }
  __shared__ u16 tile[32][33];
  const int isf = flag[0];
  const int n0 = (bx - bxo) * 32, k0 = by * 32;
  const int tx = threadIdx.x & 31, ty = threadIdx.x >> 5;
#pragma unroll
  for (int i = 0; i < 4; ++i) {
    const int k = k0 + ty + 8 * i, n = n0 + tx;
    tile[ty + 8 * i][tx] = (n < N) ? load_elem_bf16(in, (size_t)k * N + n, isf) : (u16)0;
  }
  __syncthreads();
#pragma unroll
  for (int i = 0; i < 4; ++i) {
    const int n = n0 + ty + 8 * i, k = k0 + tx;
    if (n < Npad) out[(size_t)n * K + k] = tile[tx][ty + 8 * i];
  }
}

// ---------------------------------------------------------------------------
// GEMM (m97-style 128x128 tile).
// EPI==0: relu, split-store bf16 hi+lo.  EPI==1: store f32.  EPI==2: relu, hi only.
// ---------------------------------------------------------------------------
__device__ __forceinline__ void gload_lds16(const u16* g, u16* l) {
  __builtin_amdgcn_global_load_lds((const __attribute__((address_space(1))) void*)g,
                                   (__attribute__((address_space(3))) void*)l, 16, 0, 0);
}

template <int EPI, bool HAS_LO>
__global__ __launch_bounds__(256) void gemm_bt(const u16* __restrict__ Ahi, const u16* __restrict__ Alo,
                                               const u16* __restrict__ Bt,  const float* __restrict__ bias,
                                               u16* __restrict__ Chi, u16* __restrict__ Clo,
                                               float* __restrict__ Cf,
                                               int M, int N, int K) {
  __shared__ __align__(16) u16 lA[128 * 32];
  __shared__ __align__(16) u16 lAlo[128 * 32];
  __shared__ __align__(16) u16 lB[128 * 32];
  const int tile_n = blockIdx.x * 128;
  const int tile_m = blockIdx.y * 128;
  const int lane = threadIdx.x & 63;
  const int wv   = threadIdx.x >> 6;
  const int wm = (wv & 1) * 64;
  const int wn = (wv >> 1) * 64;
  const int sr = lane >> 2;
  const int sk = (lane & 3) * 8;
  floatx4 acc[4][4] = {};

  for (int k0 = 0; k0 < K; k0 += 32) {
#pragma unroll
    for (int it = 0; it < 2; ++it) {
      const int slot = it * 4 + wv;
      const int r = slot * 16 + sr;
      gload_lds16(Ahi + (size_t)(tile_m + r) * K + k0 + sk, lA + slot * 512);
      if (HAS_LO)
        gload_lds16(Alo + (size_t)(tile_m + r) * K + k0 + sk, lAlo + slot * 512);
      gload_lds16(Bt + (size_t)(tile_n + r) * K + k0 + sk, lB + slot * 512);
    }
    __syncthreads();
    const int ro = lane & 15;
    const int qo = (lane >> 4) * 8;
    short8 af[4], bfr[4], al[4];
#pragma unroll
    for (int i = 0; i < 4; ++i) af[i] = *(const short8*)(lA + (wm + i * 16 + ro) * 32 + qo);
#pragma unroll
    for (int j = 0; j < 4; ++j) bfr[j] = *(const short8*)(lB + (wn + j * 16 + ro) * 32 + qo);
    if (HAS_LO) {
#pragma unroll
      for (int i = 0; i < 4; ++i) al[i] = *(const short8*)(lAlo + (wm + i * 16 + ro) * 32 + qo);
    }
#pragma unroll
    for (int i = 0; i < 4; ++i)
#pragma unroll
      for (int j = 0; j < 4; ++j) {
        acc[i][j] = __builtin_amdgcn_mfma_f32_16x16x32_bf16(af[i], bfr[j], acc[i][j], 0, 0, 0);
        if (HAS_LO)
          acc[i][j] = __builtin_amdgcn_mfma_f32_16x16x32_bf16(al[i], bfr[j], acc[i][j], 0, 0, 0);
      }
    __syncthreads();
  }

  const int colb = tile_n + wn + (lane & 15);
  const int rowb = tile_m + wm + (lane >> 4) * 4;
#pragma unroll
  for (int j = 0; j < 4; ++j) {
    const int col = colb + j * 16;
    const float bv = (col < N) ? bias[col] : 0.f;
#pragma unroll
    for (int i = 0; i < 4; ++i) {
#pragma unroll
      for (int v = 0; v < 4; ++v) {
        const int row = rowb + i * 16 + v;
        float val = acc[i][j][v] + bv;
        if (EPI == 0) {
          val = fmaxf(val, 0.f);
          const u16 hi = f2b(val);
          const float lo = val - b2f(hi);
          Chi[(size_t)row * N + col] = hi;
          Clo[(size_t)row * N + col] = f2b(lo);
        } else if (EPI == 2) {
          val = fmaxf(val, 0.f);
          Chi[(size_t)row * N + col] = f2b(val);
        } else {
          if (col < N) Cf[(size_t)row * N + col] = val;
        }
      }
    }
  }
}

// ---------------------------------------------------------------------------
// QP helpers
// ---------------------------------------------------------------------------
__device__ __forceinline__ f4 ld4s(const float* p) { return *(const f4*)p; }
__device__ __forceinline__ void st4s(float* p, f4 v) { *(f4*)p = v; }
__device__ __forceinline__ float dot4(f4 a, f4 b) {
  return fmaf(a.x, b.x, fmaf(a.y, b.y, fmaf(a.z, b.z, a.w * b.w)));
}
__device__ __forceinline__ f4 shx4(f4 v, int m) {
  f4 r;
  r.x = __shfl_xor(v.x, m, 64); r.y = __shfl_xor(v.y, m, 64);
  r.z = __shfl_xor(v.z, m, 64); r.w = __shfl_xor(v.w, m, 64);
  return r;
}
// XOR-swizzled float-index of f4 group g in row m (row stride 64 floats).
__device__ __forceinline__ int hQ(int m, int g) {
  return (m << 6) + (((g ^ (m & 15))) << 2);
}

// ---------------------------------------------------------------------------
// Per-batch QP solver — R5 kernel verbatim (best measured: 267 us, VGPR 64,
// no spill). 1 block/batch, 256 thr, Minv in registers, 4 blk/CU,
// 4 barriers / PDHG iter.
// ---------------------------------------------------------------------------
__global__ __launch_bounds__(256, 4) void qp_solve(const float* __restrict__ outbuf,
                                                   void* __restrict__ xs,
                                                   const int* __restrict__ flag) {
  __shared__ __align__(16) float H_s[8192];       // 32 KB (setup: Ld stride-68 + packed p)
  __shared__ __align__(16) float lam_s[128];      // also power-iter w staging
  __shared__ __align__(16) float b_s[128];
  __shared__ __align__(16) float part_s[4][64];
  __shared__ __align__(16) float rhs_s[64];
  __shared__ __align__(16) float xb_s[64];
  __shared__ __align__(16) float xp_s[64];
  __shared__ __align__(16) float q_s[64];
  __shared__ __align__(16) float buf2[2][64];
  __shared__ float tau_sh;

  const int t = threadIdx.x;
  const int w = t >> 6, l = t & 63;
  const int am = 32 * w + (l >> 1), as = l & 1;    // phase-A: row m, half s
  const int bg = l & 15, bc = l >> 4;              // phase-B: n-group, m-chunk
  const int ci = 16 * w + (l >> 2), cc = l & 3;    // M ownership: row i, col-slice c
  const int isf = flag[0];
  const float* ob = outbuf + (size_t)blockIdx.x * NOUT;

  // ---- setup: dense L (stride 68, zero-padded) + packed p ----
  float* Ld = H_s;                 // [0 .. 64*68) = 4352 floats
  float* ps = H_s + 4352;          // [4352 .. 6432)
  for (int e = t; e < 4352; e += 256) Ld[e] = 0.f;
  for (int e = t; e < NP; e += 256) ps[e] = ob[e];
  if (t < 64) q_s[t] = ob[NP + t];
  if (t >= 128 && t < 256) b_s[t - 128] = ob[NP + NQP + NHH + (t - 128)];
  __syncthreads();
  if (t < 64) {
    const int i = t + 1;
    const int d = i * (i + 1) / 2 - 1;
    const float xv = ps[d];
    ps[d] = 0.1f + (fmaxf(xv, 0.f) + log1pf(expf(-fabsf(xv))));
  }
  __syncthreads();
  for (int e = t; e < NP; e += 256) {
    int i = (int)((sqrtf(8.f * (float)e + 1.f) - 1.f) * 0.5f);
    while ((i + 1) * (i + 2) / 2 <= e) ++i;
    while (i * (i + 1) / 2 > e) --i;
    const int j = e - i * (i + 1) / 2;   // j <= i
    Ld[i * 68 + j] = ps[e];
  }
  __syncthreads();

  // ---- P = L L^T into registers M[16] (row ci, cols 16cc..16cc+15) ----
  float M[16];
#pragma unroll
  for (int jj = 0; jj < 16; ++jj) M[jj] = 0.f;
#pragma unroll
  for (int h = 0; h < 2; ++h) {
    f4 Lr[8];
#pragma unroll
    for (int g = 0; g < 8; ++g) Lr[g] = ld4s(&Ld[ci * 68 + (h * 8 + g) * 4]);
#pragma unroll
    for (int jj = 0; jj < 16; ++jj) {
      const int j = 16 * cc + jj;
      float s = 0.f;
#pragma unroll
      for (int g = 0; g < 8; ++g) s += dot4(Lr[g], ld4s(&Ld[j * 68 + (h * 8 + g) * 4]));
      M[jj] += s;
    }
  }
  __syncthreads();   // done with Ld/ps

  // ---- load H (swizzled f32), init power vector ----
  for (int e = t; e < NHH; e += 256) {
    const int m = e >> 6, n = e & 63;
    H_s[hQ(m, n >> 2) + (n & 3)] = ob[NP + NQP + e];
  }
  if (t < 64) xb_s[t] = 0.125f;
  __syncthreads();

  // ---- power iteration (10): v in xb_s, w staged in lam_s ----
  for (int pi = 0; pi < 10; ++pi) {
    {
      float s = 0.f;
#pragma unroll
      for (int k = 0; k < 8; ++k) {
        const int g = 8 * as + k;
        s += dot4(ld4s(&H_s[hQ(am, g)]), ld4s(&xb_s[4 * g]));
      }
      s += __shfl_xor(s, 1, 64);
      if (as == 0) lam_s[am] = s;
    }
    __syncthreads();
    {
      f4 u = {0.f, 0.f, 0.f, 0.f};
#pragma unroll
      for (int k = 0; k < 8; ++k) {
        const int m = 32 * w + 8 * bc + k;
        u += ld4s(&H_s[hQ(m, bg)]) * lam_s[m];
      }
      u += shx4(u, 16); u += shx4(u, 32);
      if (l < 16) st4s(&part_s[w][4 * bg], u);
    }
    __syncthreads();
    if (t < 64) {
      const float u = part_s[0][t] + part_s[1][t] + part_s[2][t] + part_s[3][t];
      float ss = u * u;
#pragma unroll
      for (int o = 1; o <= 32; o <<= 1) ss += __shfl_xor(ss, o, 64);
      xb_s[t] = u / (sqrtf(ss) + 1e-12f);
    }
    __syncthreads();
  }
  // ---- tau = 0.9 / (||H v|| + 1e-6) ----
  {
    float s = 0.f;
#pragma unroll
    for (int k = 0; k < 8; ++k) {
      const int g = 8 * as + k;
      s += dot4(ld4s(&H_s[hQ(am, g)]), ld4s(&xb_s[4 * g]));
    }
    s += __shfl_xor(s, 1, 64);
    if (as == 0) lam_s[am] = s;
  }
  __syncthreads();
  if (t < 64) {
    const float a = lam_s[t], bb = lam_s[t + 64];
    float ss = a * a + bb * bb;
#pragma unroll
    for (int o = 1; o <= 32; o <<= 1) ss += __shfl_xor(ss, o, 64);
    if (t == 0) tau_sh = 0.9f / (sqrtf(ss) + 1e-6f);
  }
  __syncthreads();
  const float tau = tau_sh;

  // ---- M = I + tau*P (registers) ----
#pragma unroll
  for (int jj = 0; jj < 16; ++jj)
    M[jj] = tau * M[jj] + ((16 * cc + jj == ci) ? 1.0f : 0.0f);

  // ---- Gauss-Jordan inversion in registers (SPD, pivots >= 1) ----
  if (ci == 0) {
#pragma unroll
    for (int jj = 0; jj < 16; ++jj) buf2[0][16 * cc + jj] = M[jj];
  }
  __syncthreads();
#pragma unroll
  for (int k = 0; k < 64; ++k) {
    const int kb = k & 1;
    const int kc = k >> 4;   // col-slice owner of column k
    const float d = 1.0f / buf2[kb][k];
    f4 rv[4];
#pragma unroll
    for (int u = 0; u < 4; ++u) rv[u] = ld4s(&buf2[kb][16 * cc + 4 * u]);
    const float f = __shfl(M[k & 15], (l & 60) | kc, 64);  // M[i][k], pre-update
    if (ci == k) {
#pragma unroll
      for (int jj = 0; jj < 16; ++jj) M[jj] = rv[jj >> 2][jj & 3] * d;
      if (cc == kc) M[k & 15] = d;
    } else {
#pragma unroll
      for (int jj = 0; jj < 16; ++jj)
        M[jj] = fmaf(-f, rv[jj >> 2][jj & 3] * d, M[jj]);
      if (cc == kc) M[k & 15] = -f * d;
    }
    if (k < 63 && ci == k + 1) {
#pragma unroll
      for (int jj = 0; jj < 16; ++jj) buf2[1 - kb][16 * cc + jj] = M[jj];
    }
    __syncthreads();
  }

  // ---- c0 = tau * (Minv q) ----
  float c0;
  {
    float acc = 0.f;
#pragma unroll
    for (int u = 0; u < 4; ++u) {
      const f4 qv = ld4s(&q_s[16 * cc + 4 * u]);
      acc = fmaf(M[4 * u + 0], qv.x, acc);
      acc = fmaf(M[4 * u + 1], qv.y, acc);
      acc = fmaf(M[4 * u + 2], qv.z, acc);
      acc = fmaf(M[4 * u + 3], qv.w, acc);
    }
    acc += __shfl_xor(acc, 1, 64);
    acc += __shfl_xor(acc, 2, 64);
    c0 = tau * acc;
  }

  // ---- PDHG (50 iters), 4 barriers/iter ----
  if (t < 64) { xb_s[t] = 0.f; xp_s[t] = 0.f; }
  float lam = 0.f, xpr = 0.f;
  const float br = b_s[am];
  __syncthreads();

  for (int it = 0; it < 50; ++it) {
    // A: lam = relu(lam - tau*(H xbar + b))   [2 lanes/row, 1 shfl]
    {
      float s = 0.f;
#pragma unroll
      for (int k = 0; k < 8; ++k) {
        const int g = 8 * as + k;
        s += dot4(ld4s(&H_s[hQ(am, g)]), ld4s(&xb_s[4 * g]));
      }
      s += __shfl_xor(s, 1, 64);
      lam = fmaxf(lam - tau * (s + br), 0.f);
      if (as == 0) lam_s[am] = lam;
    }
    __syncthreads();
    // B: per-wave partials of H^T lam
    {
      f4 u = {0.f, 0.f, 0.f, 0.f};
#pragma unroll
      for (int k = 0; k < 8; ++k) {
        const int m = 32 * w + 8 * bc + k;
        u += ld4s(&H_s[hQ(m, bg)]) * lam_s[m];
      }
      u += shx4(u, 16); u += shx4(u, 32);
      if (l < 16) st4s(&part_s[w][4 * bg], u);
    }
    __syncthreads();
    // C1: rhs = xp + tau * (sum of wave partials)   [64 threads]
    if (t < 64) {
      const float uu = part_s[0][t] + part_s[1][t] + part_s[2][t] + part_s[3][t];
      rhs_s[t] = xp_s[t] + tau * uu;
    }
    __syncthreads();
    // C2: xn = Minv*rhs - c0   [register Minv, broadcast rhs reads]
    {
      float acc = 0.f;
#pragma unroll
      for (int u = 0; u < 4; ++u) {
        const f4 rv = ld4s(&rhs_s[16 * cc + 4 * u]);
        acc = fmaf(M[4 * u + 0], rv.x, acc);
        acc = fmaf(M[4 * u + 1], rv.y, acc);
        acc = fmaf(M[4 * u + 2], rv.z, acc);
        acc = fmaf(M[4 * u + 3], rv.w, acc);
      }
      acc += __shfl_xor(acc, 1, 64);
      acc += __shfl_xor(acc, 2, 64);
      if (cc == 0) {
        const float xn = acc - c0;
        xp_s[ci] = xn;
        xb_s[ci] = 2.f * xn - xpr;
        xpr = xn;
      }
    }
    __syncthreads();
  }

  if (cc == 0) {
    const size_t oi = (size_t)blockIdx.x * NQP + ci;
    if (isf) ((float*)xs)[oi] = xpr;
    else     ((u16*)xs)[oi]   = f2b(xpr);
  }
}

// ---------------------------------------------------------------------------
extern "C" void kernel_launch(void* const* d_in, const int* in_sizes, int n_in,
                              void* d_out, int out_size, void* d_ws, size_t ws_size,
                              hipStream_t stream) {
  const void* x  = d_in[0];
  const void* W1 = d_in[1];
  const void* b1 = d_in[2];
  const void* W2 = d_in[3];
  const void* b2 = d_in[4];
  const void* W3 = d_in[5];
  const void* b3 = d_in[6];

  char* ws = (char*)d_ws;
  size_t off = 0;
  auto take = [&](size_t bytes) -> char* {
    char* r = ws + off;
    off += (bytes + 255) & ~(size_t)255;
    return r;
  };
  int*   flag = (int*)take(256);
  float* bf1  = (float*)take(1024 * 4);
  float* bf2  = (float*)take(1024 * 4);
  float* bf3  = (float*)take((size_t)NOUT * 4);
  u16*   W3t  = (u16*)take((size_t)NOUTP * 1024 * 2);
  u16*   h2hi = (u16*)take(1024ull * 1024 * 2);
  char*  region = take(1024ull * NOUT * 4);   // outf, overlaid below
  float* outf = (float*)region;
  u16* xb   = (u16*)(region + 0);                 // 1 MB
  u16* W1t  = (u16*)(region + (1u << 20));        // 1 MB
  u16* W2t  = (u16*)(region + (2u << 20));        // 2 MB
  u16* h1hi = (u16*)(region + (4u << 20));        // 2 MB
  u16* h1lo = (u16*)(region + (6u << 20));        // 2 MB
  (void)ws_size; (void)in_sizes; (void)n_in; (void)out_size;

  detect_dtype<<<dim3(1), 256, 0, stream>>>((const u16*)W1, flag);

  convert_bf16<<<dim3(512), 256, 0, stream>>>(x, xb, 1024 * 512, flag);
  conv_biases<<<dim3(49), 256, 0, stream>>>(b1, b2, b3, bf1, bf2, bf3, flag);
  transpose_all<<<dim3(392, 32), 256, 0, stream>>>(W1, W2, W3, W1t, W2t, W3t, flag);

  // GEMM1: h1 = relu(x @ W1 + b1), split store (hi+lo)
  gemm_bt<0, false><<<dim3(8, 8), 256, 0, stream>>>(xb, nullptr, W1t, bf1,
                                                    h1hi, h1lo, nullptr, 1024, 1024, 512);
  // GEMM2: h2 = relu((h1hi+h1lo) @ W2 + b2), store correctly-rounded hi only
  gemm_bt<2, true><<<dim3(8, 8), 256, 0, stream>>>(h1hi, h1lo, W2t, bf2,
                                                   h2hi, nullptr, nullptr, 1024, 1024, 1024);
  // GEMM3: out = h2hi @ W3 + b3 (single chain, f32 out)
  gemm_bt<1, false><<<dim3(NOUTP / 128, 8), 256, 0, stream>>>(h2hi, nullptr, W3t, bf3,
                                                              nullptr, nullptr, outf, 1024, NOUT, 1024);
  qp_solve<<<dim3(1024), 256, 0, stream>>>(outf, d_out, flag);
}